// Round 11
// baseline (92.583 us; speedup 1.0000x reference)
//
#include <hip/hip_runtime.h>
#include <hip/hip_bf16.h>

#define NN 8192

using f32x4 = __attribute__((ext_vector_type(4))) float;
using i32x4v = __attribute__((ext_vector_type(4))) int;
using i32x8v = __attribute__((ext_vector_type(8))) int;

#if __has_builtin(__builtin_amdgcn_exp2f)
#define EXP2(x) __builtin_amdgcn_exp2f(x)
#else
#define EXP2(x) __expf((x) * 0.69314718056f)
#endif

// ---- async global->LDS 16B (wave-uniform base + lane*16 layout) ----
__device__ __forceinline__ void gl_lds16(const void* g, void* l) {
  __builtin_amdgcn_global_load_lds(
      (const __attribute__((address_space(1))) unsigned int*)(unsigned long long)g,
      (__attribute__((address_space(3))) unsigned int*)(unsigned int)(unsigned long long)l,
      16, 0, 0);
}

// ---- fp8 e4m3 (OCP) pack: 4 floats -> 4 bytes ----
#if __has_builtin(__builtin_amdgcn_cvt_pk_fp8_f32)
__device__ __forceinline__ unsigned pk4_fp8(float x0, float x1, float x2, float x3) {
  unsigned w = (unsigned)__builtin_amdgcn_cvt_pk_fp8_f32(x0, x1, 0, false);
  w = (unsigned)__builtin_amdgcn_cvt_pk_fp8_f32(x2, x3, (int)w, true);
  return w;
}
#else
__device__ __forceinline__ unsigned f8_1(float f) {   // scalar e4m3fn RNE fallback
  unsigned u = __float_as_uint(f);
  unsigned s = (u >> 24) & 0x80u;
  float a = fabsf(f);
  if (a < 0.015625f) {                                 // subnormal: step 2^-9
    unsigned m = (unsigned)rintf(a * 512.0f);
    return s | (m > 7u ? 8u : m);                      // carries into exp 1 naturally
  }
  if (a > 448.0f) return s | 0x7Eu;
  unsigned au = u & 0x7FFFFFFFu;
  unsigned e = (au >> 23) - 127u + 7u;                 // e4m3 biased exponent
  unsigned m23 = au & 0x7FFFFFu;
  unsigned m = m23 >> 20;
  unsigned rem = m23 & 0xFFFFFu;
  if (rem > 0x80000u || (rem == 0x80000u && (m & 1u))) {
    if (++m == 8u) { m = 0u; ++e; }
  }
  return s | (e << 3) | m;
}
__device__ __forceinline__ unsigned pk4_fp8(float x0, float x1, float x2, float x3) {
  return f8_1(x0) | (f8_1(x1) << 8) | (f8_1(x2) << 16) | (f8_1(x3) << 24);
}
#endif

// ---------------- kernel 1: normalize rows -> fp8, logit_p, zero bandsum+counter ----------------
__global__ __launch_bounds__(256) void k_prep(const float* __restrict__ enc,
                                              const float* __restrict__ dec,
                                              uint2* __restrict__ A8,
                                              uint2* __restrict__ B8,
                                              float* __restrict__ logit_p,
                                              float* __restrict__ bandsum,
                                              unsigned* __restrict__ counter) {
  const int t = threadIdx.x;
  const int l16 = t & 15;
  const int row = blockIdx.x * 16 + (t >> 4);
  const int tid = blockIdx.x * 256 + t;
  if (tid < 64 * 256) bandsum[tid] = 0.0f;
  if (tid == 64 * 256) *counter = 0u;

  const float4* e4 = reinterpret_cast<const float4*>(enc) + (size_t)row * 32 + l16 * 2;
  const float4* d4 = reinterpret_cast<const float4*>(dec) + (size_t)row * 32 + l16 * 2;
  float4 e0 = e4[0], e1 = e4[1];
  float4 d0 = d4[0], d1 = d4[1];

  float se = e0.x*e0.x + e0.y*e0.y + e0.z*e0.z + e0.w*e0.w
           + e1.x*e1.x + e1.y*e1.y + e1.z*e1.z + e1.w*e1.w;
  float sd = d0.x*d0.x + d0.y*d0.y + d0.z*d0.z + d0.w*d0.w
           + d1.x*d1.x + d1.y*d1.y + d1.z*d1.z + d1.w*d1.w;
  float sp = e0.x*d0.x + e0.y*d0.y + e0.z*d0.z + e0.w*d0.w
           + e1.x*d1.x + e1.y*d1.y + e1.z*d1.z + e1.w*d1.w;
#pragma unroll
  for (int off = 1; off < 16; off <<= 1) {
    se += __shfl_xor(se, off);
    sd += __shfl_xor(sd, off);
    sp += __shfl_xor(sp, off);
  }
  float ie = rsqrtf(se), id = rsqrtf(sd);

  uint2 ua, ub;
  ua.x = pk4_fp8(e0.x * ie, e0.y * ie, e0.z * ie, e0.w * ie);
  ua.y = pk4_fp8(e1.x * ie, e1.y * ie, e1.z * ie, e1.w * ie);
  ub.x = pk4_fp8(d0.x * id, d0.y * id, d0.z * id, d0.w * id);
  ub.y = pk4_fp8(d1.x * id, d1.y * id, d1.z * id, d1.w * id);
  A8[(size_t)row * 16 + l16] = ua;   // row stride 128 B (128 fp8)
  B8[(size_t)row * 16 + l16] = ub;

  if (l16 == 0) {
    float en = se * ie, dn = sd * id;                 // sqrt via x*rsqrt(x)
    float s  = sp / (en * dn + 1e-5f);
    logit_p[row] = -fmaxf(1.25f - s, 0.0f) * (s - 0.75f) * 64.0f;
  }
}

// read a 32B k-fragment (k-bytes [2q*16, 2q*16+32)) from the xor-swizzled LDS tile
__device__ __forceinline__ i32x8v ld_frag32(const unsigned char* __restrict__ buf,
                                            int rowbase, int q2, int x7) {
  i32x4v lo = *reinterpret_cast<const i32x4v*>(buf + rowbase + ((q2 ^ x7) * 16));
  i32x4v hi = *reinterpret_cast<const i32x4v*>(buf + rowbase + (((q2 + 1) ^ x7) * 16));
  i32x8v r;
  r[0] = lo[0]; r[1] = lo[1]; r[2] = lo[2]; r[3] = lo[3];
  r[4] = hi[0]; r[5] = hi[1]; r[6] = hi[2]; r[7] = hi[3];
  return r;
}

// epilogue: 92.33*(max(sn,-0.25)^2 - 0.0625) in the exp2 argument
// sqrt(64*log2(e)) = 9.6089793 ; 64*log2(e)/16 = 5.7707802
__device__ __forceinline__ void epi(const f32x4 (&acc)[4][4], float (&dreg)[28]) {
#pragma unroll
  for (int dlt = -3; dlt <= 3; ++dlt) {
#pragma unroll
    for (int g = 0; g < 4; ++g) {
      float s = 0.0f;
#pragma unroll
      for (int r = 0; r < 4; ++r) {
        int c = r + dlt;
        if (c < 0 || c > 3) continue;
        float x  = fmaxf(acc[r][c][g], -0.25f);
        float wv = x * 9.6089793f;
        s += EXP2(fmaf(wv, wv, -5.7707802f));
      }
      dreg[(dlt + 3) * 4 + g] += s;
    }
  }
}

// ---------------- kernel 2: v8 + deferred epilogue (one-acc software pipeline) ----------------
// v9: window body reordered to {stage issue, ALL 16 ds_read_b128, epilogue of
// PREVIOUS window (reg-only, fills the ds_read latency shadow), 16 MFMA
// (fresh-C into the same acc)}. Unlike v6's failed 2-acc pipeline, acc(prev)'s
// liveness ends exactly where the MFMAs rewrite it -> one 64-reg accumulator,
// peak ~180 regs < 256 budget at (256,2). Final epilogue peeled after loop.
__global__ __launch_bounds__(256, 2) void k_main(const unsigned char* __restrict__ A,
                                                 const unsigned char* __restrict__ B,
                                                 float* __restrict__ bandsum,
                                                 const float* __restrict__ logit_p,
                                                 unsigned* __restrict__ counter,
                                                 float* __restrict__ out) {
  __shared__ __align__(16) unsigned char As[2 * 16384];   // 2 bufs x 128 rows x 128 B
  __shared__ __align__(16) unsigned char Bs[2 * 16384];
  __shared__ float part[4][256];
  __shared__ unsigned lastFlag;

  const int t  = threadIdx.x;
  const int T  = blockIdx.x;   // band: tiles with (bx-by)&63 == T
  const int sp = blockIdx.y;   // split along the band

#pragma unroll
  for (int q = 0; q < 4; ++q) part[q][t] = 0.0f;

  const int lane = t & 63;
  const int w = t >> 6, wrow = w >> 1, wcol = w & 1;
  const int l15 = lane & 15, quad = lane >> 4;
  const int x7 = l15 & 7;
  const int q2 = quad * 2;
#if !__has_builtin(__builtin_amdgcn_mfma_scale_f32_16x16x128_f8f6f4)
  const int qh = quad >> 1, ql8 = (quad & 1) * 8;
#endif

  // staging: row-within-32 = t>>3, 16B-chunk slot = t&7, xor swizzle
  const int rl = t >> 3;
  const int lgoff = rl * 128 + ((t & 7) ^ (rl & 7)) * 16;  // global byte offset in 32-row group
  const int lloff = t * 16;                                 // LDS byte offset (contiguous)

  const char* Ab = (const char*)A;
  const char* Bb = (const char*)B;

  float dreg[28];
#pragma unroll
  for (int i = 0; i < 28; ++i) dreg[i] = 0.0f;

  // frag read bases (byte offsets within a 16 KB buffer)
  const int arow = (wrow * 64 + l15) * 128;
  const int brow = (wcol * 64 + l15) * 128;

  // ---- stage tile 0 into buf 0 ----
  {
    const int by = sp * 8;
    const int bx = (by + T) & 63;
    const char* Ag = Ab + (size_t)by * 16384 + lgoff;
    const char* Bg = Bb + (size_t)bx * 16384 + lgoff;
#pragma unroll
    for (int j = 0; j < 4; ++j) {
      gl_lds16(Ag + j * 4096, (char*)As + j * 4096 + lloff);
      gl_lds16(Bg + j * 4096, (char*)Bs + j * 4096 + lloff);
    }
  }
  __syncthreads();   // vmcnt(0): tile 0 staged

  const f32x4 zv4 = {0.f, 0.f, 0.f, 0.f};   // persistent zero C-operand
  f32x4 acc[4][4];

  for (int it = 0; it < 8; ++it) {
    const int p = it & 1;

    if (it < 7) {    // issue next tile's stage into the other buffer; lands by tile-end barrier
      const int by = sp * 8 + it + 1;
      const int bx = (by + T) & 63;
      const char* Ag = Ab + (size_t)by * 16384 + lgoff;
      const char* Bg = Bb + (size_t)bx * 16384 + lgoff;
      char* Ad = (char*)As + (p ^ 1) * 16384 + lloff;
      char* Bd = (char*)Bs + (p ^ 1) * 16384 + lloff;
#pragma unroll
      for (int j = 0; j < 4; ++j) {
        gl_lds16(Ag + j * 4096, Ad + j * 4096);
        gl_lds16(Bg + j * 4096, Bd + j * 4096);
      }
    }

    const unsigned char* Abuf = (const unsigned char*)As + p * 16384;
    const unsigned char* Bbuf = (const unsigned char*)Bs + p * 16384;

#if __has_builtin(__builtin_amdgcn_mfma_scale_f32_16x16x128_f8f6f4)
    // ---- issue ALL fragment loads first (16 x ds_read_b128) ----
    i32x8v af[4], bf[4];
#pragma unroll
    for (int c = 0; c < 4; ++c) bf[c] = ld_frag32(Bbuf, brow + c * 2048, q2, x7);
#pragma unroll
    for (int r = 0; r < 4; ++r) af[r] = ld_frag32(Abuf, arow + r * 2048, q2, x7);

    // ---- previous window's epilogue: reg-only, fills the ds_read shadow ----
    if (it) epi(acc, dreg);

    // ---- 16 MFMA, fresh-C (D != C) into the single accumulator ----
#pragma unroll
    for (int r = 0; r < 4; ++r)
#pragma unroll
      for (int c = 0; c < 4; ++c)
        acc[r][c] = __builtin_amdgcn_mfma_scale_f32_16x16x128_f8f6f4(
            af[r], bf[c], zv4, 0, 0,                       // C = shared zero quad
            0, 0x7F7F7F7F, 0, 0x7F7F7F7F);                 // unit scales (e8m0 127 = 2^0)
#else
    {
      if (it) epi(acc, dreg);
      const f32x4 zv = {0.f, 0.f, 0.f, 0.f};
#pragma unroll
      for (int r = 0; r < 4; ++r)
#pragma unroll
        for (int c = 0; c < 4; ++c) acc[r][c] = zv;
#pragma unroll
      for (int ks = 0; ks < 4; ++ks) {
        long a[4], b[4];
        const int off = (((ks * 2 + qh) ^ x7) * 16) + ql8;   // swizzled 8B k-chunk
#pragma unroll
        for (int r = 0; r < 4; ++r)
          a[r] = *reinterpret_cast<const long*>(Abuf + arow + r * 2048 + off);
#pragma unroll
        for (int c = 0; c < 4; ++c)
          b[c] = *reinterpret_cast<const long*>(Bbuf + brow + c * 2048 + off);
#pragma unroll
        for (int r = 0; r < 4; ++r)
#pragma unroll
          for (int c = 0; c < 4; ++c)
            acc[r][c] = __builtin_amdgcn_mfma_f32_16x16x32_fp8_fp8(a[r], b[c], acc[r][c], 0, 0, 0);
      }
    }
#endif

    __syncthreads();   // one barrier/tile: drains ds_reads of buf p AND stage into buf p^1
  }

  // final window's epilogue (pipeline drain)
  epi(acc, dreg);

  // ---- single flush: shfl tree over 4-lane collision groups -> LDS -> global ----
  const int  Qoff = (wcol - wrow) * 64 + 127;
  const int  v    = l15 - quad * 4;
  const bool leader = (quad == 0) || (l15 <= 3);
  const bool ok1 = (l15 <= 11) && (quad <= 2);
  const bool ok2 = (l15 <= 7)  && (quad <= 1);

#pragma unroll
  for (int dlt = -3; dlt <= 3; ++dlt) {
#pragma unroll
    for (int g = 0; g < 4; ++g) {
      float s = dreg[(dlt + 3) * 4 + g];
      float t1 = __shfl_down(s, 20); s += ok1 ? t1 : 0.0f;  // partner quad+1
      float t2 = __shfl_down(s, 40); s += ok2 ? t2 : 0.0f;  // partners quad+2, quad+3
      int ld = Qoff + dlt * 16 - g + v;
      if (leader) unsafeAtomicAdd(&part[w][ld], s);         // distinct ld per leader
    }
  }
  __syncthreads();

  // band-0 slot 127 corresponds to d=0 only, which the tail skips
  if (t < 255) {
    float vv = part[0][t] + part[1][t] + part[2][t] + part[3][t];
    unsafeAtomicAdd(&bandsum[T * 256 + t], vv);
  }

  // ---- last-block-done detection (device-scope atomics; counter bump after
  //      the bandsum adds; no release fence needed) ----
  __syncthreads();
  if (t == 0) lastFlag = (atomicAdd(counter, 1u) == 511u) ? 1u : 0u;
  __syncthreads();
  if (!lastFlag) return;

  // ================= scalar tail (one block, 256 threads, batched loads) =================
  __threadfence();          // acquire: invalidate stale lines so bandsum loads are fresh
  float* sm = part[0];

  float lp[32];
#pragma unroll
  for (int k = 0; k < 32; ++k) lp[k] = logit_p[t + 256 * k];

  float m = lp[0];
#pragma unroll
  for (int k = 1; k < 32; ++k) m = fmaxf(m, lp[k]);
#pragma unroll
  for (int off = 32; off; off >>= 1) m = fmaxf(m, __shfl_down(m, off));
  if (lane == 0) sm[w] = m;
  __syncthreads();
  m = fmaxf(fmaxf(sm[0], sm[1]), fmaxf(sm[2], sm[3]));
  __syncthreads();

  float s = 0.0f;
#pragma unroll
  for (int k = 0; k < 32; ++k) s += __expf(lp[k] - m);
#pragma unroll
  for (int off = 32; off; off >>= 1) s += __shfl_down(s, off);
  if (lane == 0) sm[w] = s;
  __syncthreads();
  s = sm[0] + sm[1] + sm[2] + sm[3];
  float lse_p = m + __logf(s);
  __syncthreads();

  // thread t handles d = t + 256k: d>>7 = (t>>7) + 2k, d&127 = t&127
  const int o  = t & 127;
  const int hi = t >> 7;
  float bs1[32], bs2[32];
#pragma unroll
  for (int k = 0; k < 32; ++k) {
    int Ta = hi + 2 * k;
    bs1[k] = bandsum[Ta * 256 + o + 127];
    bs2[k] = o ? bandsum[((Ta + 1) & 63) * 256 + o - 1] : 0.0f;
  }
  float tacc = 0.0f;
#pragma unroll
  for (int k = 0; k < 32; ++k) {
    if (t == 0 && k == 0) continue;   // d=0 excluded
    float se = bs1[k] + bs2[k];
    float x = __logf(se) + lse_p;
    tacc += fmaxf(x, 0.0f) + __logf(1.0f + __expf(-fabsf(x)));
  }
#pragma unroll
  for (int off = 32; off; off >>= 1) tacc += __shfl_down(tacc, off);
  if (lane == 0) sm[w] = tacc;
  __syncthreads();
  if (t == 0) out[0] = (sm[0] + sm[1] + sm[2] + sm[3]) * (1.0f / 8191.0f);
}

// ---------------- launcher ----------------
extern "C" void kernel_launch(void* const* d_in, const int* in_sizes, int n_in,
                              void* d_out, int out_size, void* d_ws, size_t ws_size,
                              hipStream_t stream) {
  const float* enc = (const float*)d_in[0];
  const float* dec = (const float*)d_in[1];
  float* ws = (float*)d_ws;

  float*    logit_p = ws;                               // 8192
  float*    bandsum = ws + 8192;                        // 64*256 = 16384
  unsigned* counter = (unsigned*)(ws + 8192 + 16384);   // 1 (+pad)
  uint2*    A8      = (uint2*)(ws + 8192 + 16384 + 256);     // 8192x128 fp8 = 1 MB
  uint2*    B8      = (uint2*)((char*)A8 + 1048576);
  float*    out     = (float*)d_out;

  k_prep<<<NN / 16, 256, 0, stream>>>(enc, dec, A8, B8, logit_p, bandsum, counter);
  dim3 grid(64, 8);
  k_main<<<grid, 256, 0, stream>>>((const unsigned char*)A8, (const unsigned char*)B8,
                                   bandsum, logit_p, counter, out);
}

// Round 12
// 92.379 us; speedup vs baseline: 1.0022x; 1.0022x over previous
//
#include <hip/hip_runtime.h>
#include <hip/hip_bf16.h>

#define NN 8192

using f32x4 = __attribute__((ext_vector_type(4))) float;
using i32x4v = __attribute__((ext_vector_type(4))) int;
using i32x8v = __attribute__((ext_vector_type(8))) int;

#if __has_builtin(__builtin_amdgcn_exp2f)
#define EXP2(x) __builtin_amdgcn_exp2f(x)
#else
#define EXP2(x) __expf((x) * 0.69314718056f)
#endif

// ---- async global->LDS 16B (wave-uniform base + lane*16 layout) ----
__device__ __forceinline__ void gl_lds16(const void* g, void* l) {
  __builtin_amdgcn_global_load_lds(
      (const __attribute__((address_space(1))) unsigned int*)(unsigned long long)g,
      (__attribute__((address_space(3))) unsigned int*)(unsigned int)(unsigned long long)l,
      16, 0, 0);
}

// ---- fp8 e4m3 (OCP) pack: 4 floats -> 4 bytes ----
#if __has_builtin(__builtin_amdgcn_cvt_pk_fp8_f32)
__device__ __forceinline__ unsigned pk4_fp8(float x0, float x1, float x2, float x3) {
  unsigned w = (unsigned)__builtin_amdgcn_cvt_pk_fp8_f32(x0, x1, 0, false);
  w = (unsigned)__builtin_amdgcn_cvt_pk_fp8_f32(x2, x3, (int)w, true);
  return w;
}
#else
__device__ __forceinline__ unsigned f8_1(float f) {   // scalar e4m3fn RNE fallback
  unsigned u = __float_as_uint(f);
  unsigned s = (u >> 24) & 0x80u;
  float a = fabsf(f);
  if (a < 0.015625f) {                                 // subnormal: step 2^-9
    unsigned m = (unsigned)rintf(a * 512.0f);
    return s | (m > 7u ? 8u : m);                      // carries into exp 1 naturally
  }
  if (a > 448.0f) return s | 0x7Eu;
  unsigned au = u & 0x7FFFFFFFu;
  unsigned e = (au >> 23) - 127u + 7u;                 // e4m3 biased exponent
  unsigned m23 = au & 0x7FFFFFu;
  unsigned m = m23 >> 20;
  unsigned rem = m23 & 0xFFFFFu;
  if (rem > 0x80000u || (rem == 0x80000u && (m & 1u))) {
    if (++m == 8u) { m = 0u; ++e; }
  }
  return s | (e << 3) | m;
}
__device__ __forceinline__ unsigned pk4_fp8(float x0, float x1, float x2, float x3) {
  return f8_1(x0) | (f8_1(x1) << 8) | (f8_1(x2) << 16) | (f8_1(x3) << 24);
}
#endif

// ---------------- kernel 1: normalize rows -> fp8, logit_p, zero bandsum+counter ----------------
__global__ __launch_bounds__(256) void k_prep(const float* __restrict__ enc,
                                              const float* __restrict__ dec,
                                              uint2* __restrict__ A8,
                                              uint2* __restrict__ B8,
                                              float* __restrict__ logit_p,
                                              float* __restrict__ bandsum,
                                              unsigned* __restrict__ counter) {
  const int t = threadIdx.x;
  const int l16 = t & 15;
  const int row = blockIdx.x * 16 + (t >> 4);
  const int tid = blockIdx.x * 256 + t;
  if (tid < 64 * 256) bandsum[tid] = 0.0f;
  if (tid == 64 * 256) *counter = 0u;

  const float4* e4 = reinterpret_cast<const float4*>(enc) + (size_t)row * 32 + l16 * 2;
  const float4* d4 = reinterpret_cast<const float4*>(dec) + (size_t)row * 32 + l16 * 2;
  float4 e0 = e4[0], e1 = e4[1];
  float4 d0 = d4[0], d1 = d4[1];

  float se = e0.x*e0.x + e0.y*e0.y + e0.z*e0.z + e0.w*e0.w
           + e1.x*e1.x + e1.y*e1.y + e1.z*e1.z + e1.w*e1.w;
  float sd = d0.x*d0.x + d0.y*d0.y + d0.z*d0.z + d0.w*d0.w
           + d1.x*d1.x + d1.y*d1.y + d1.z*d1.z + d1.w*d1.w;
  float sp = e0.x*d0.x + e0.y*d0.y + e0.z*d0.z + e0.w*d0.w
           + e1.x*d1.x + e1.y*d1.y + e1.z*d1.z + e1.w*d1.w;
#pragma unroll
  for (int off = 1; off < 16; off <<= 1) {
    se += __shfl_xor(se, off);
    sd += __shfl_xor(sd, off);
    sp += __shfl_xor(sp, off);
  }
  float ie = rsqrtf(se), id = rsqrtf(sd);

  uint2 ua, ub;
  ua.x = pk4_fp8(e0.x * ie, e0.y * ie, e0.z * ie, e0.w * ie);
  ua.y = pk4_fp8(e1.x * ie, e1.y * ie, e1.z * ie, e1.w * ie);
  ub.x = pk4_fp8(d0.x * id, d0.y * id, d0.z * id, d0.w * id);
  ub.y = pk4_fp8(d1.x * id, d1.y * id, d1.z * id, d1.w * id);
  A8[(size_t)row * 16 + l16] = ua;   // row stride 128 B (128 fp8)
  B8[(size_t)row * 16 + l16] = ub;

  if (l16 == 0) {
    float en = se * ie, dn = sd * id;                 // sqrt via x*rsqrt(x)
    float s  = sp / (en * dn + 1e-5f);
    logit_p[row] = -fmaxf(1.25f - s, 0.0f) * (s - 0.75f) * 64.0f;
  }
}

// read a 32B k-fragment (k-bytes [2q*16, 2q*16+32)) from the xor-swizzled LDS tile
__device__ __forceinline__ i32x8v ld_frag32(const unsigned char* __restrict__ buf,
                                            int rowbase, int q2, int x7) {
  i32x4v lo = *reinterpret_cast<const i32x4v*>(buf + rowbase + ((q2 ^ x7) * 16));
  i32x4v hi = *reinterpret_cast<const i32x4v*>(buf + rowbase + (((q2 + 1) ^ x7) * 16));
  i32x8v r;
  r[0] = lo[0]; r[1] = lo[1]; r[2] = lo[2]; r[3] = lo[3];
  r[4] = hi[0]; r[5] = hi[1]; r[6] = hi[2]; r[7] = hi[3];
  return r;
}

// epilogue: 92.33*(max(sn,-0.25)^2 - 0.0625) in the exp2 argument
// sqrt(64*log2(e)) = 9.6089793 ; 64*log2(e)/16 = 5.7707802
__device__ __forceinline__ void epi(const f32x4 (&acc)[4][4], float (&dreg)[28]) {
#pragma unroll
  for (int dlt = -3; dlt <= 3; ++dlt) {
#pragma unroll
    for (int g = 0; g < 4; ++g) {
      float s = 0.0f;
#pragma unroll
      for (int r = 0; r < 4; ++r) {
        int c = r + dlt;
        if (c < 0 || c > 3) continue;
        float x  = fmaxf(acc[r][c][g], -0.25f);
        float wv = x * 9.6089793f;
        s += EXP2(fmaf(wv, wv, -5.7707802f));
      }
      dreg[(dlt + 3) * 4 + g] += s;
    }
  }
}

// ---------------- kernel 2: v9 + s_setprio(1) around the MFMA cluster (T5) ----------------
// v10: single change vs v9. Two blocks/CU run mutually-unsynchronized windows;
// when one block's waves are in the VALU/trans epilogue and the other's are
// entering MFMA, setprio(1) gives the MFMA wave issue priority so the matrix
// pipe stays fed (T5 mechanism: helps phase-diverse co-residents, null on
// lockstep structures). No register/LDS/layout change.
__global__ __launch_bounds__(256, 2) void k_main(const unsigned char* __restrict__ A,
                                                 const unsigned char* __restrict__ B,
                                                 float* __restrict__ bandsum,
                                                 const float* __restrict__ logit_p,
                                                 unsigned* __restrict__ counter,
                                                 float* __restrict__ out) {
  __shared__ __align__(16) unsigned char As[2 * 16384];   // 2 bufs x 128 rows x 128 B
  __shared__ __align__(16) unsigned char Bs[2 * 16384];
  __shared__ float part[4][256];
  __shared__ unsigned lastFlag;

  const int t  = threadIdx.x;
  const int T  = blockIdx.x;   // band: tiles with (bx-by)&63 == T
  const int sp = blockIdx.y;   // split along the band

#pragma unroll
  for (int q = 0; q < 4; ++q) part[q][t] = 0.0f;

  const int lane = t & 63;
  const int w = t >> 6, wrow = w >> 1, wcol = w & 1;
  const int l15 = lane & 15, quad = lane >> 4;
  const int x7 = l15 & 7;
  const int q2 = quad * 2;
#if !__has_builtin(__builtin_amdgcn_mfma_scale_f32_16x16x128_f8f6f4)
  const int qh = quad >> 1, ql8 = (quad & 1) * 8;
#endif

  // staging: row-within-32 = t>>3, 16B-chunk slot = t&7, xor swizzle
  const int rl = t >> 3;
  const int lgoff = rl * 128 + ((t & 7) ^ (rl & 7)) * 16;  // global byte offset in 32-row group
  const int lloff = t * 16;                                 // LDS byte offset (contiguous)

  const char* Ab = (const char*)A;
  const char* Bb = (const char*)B;

  float dreg[28];
#pragma unroll
  for (int i = 0; i < 28; ++i) dreg[i] = 0.0f;

  // frag read bases (byte offsets within a 16 KB buffer)
  const int arow = (wrow * 64 + l15) * 128;
  const int brow = (wcol * 64 + l15) * 128;

  // ---- stage tile 0 into buf 0 ----
  {
    const int by = sp * 8;
    const int bx = (by + T) & 63;
    const char* Ag = Ab + (size_t)by * 16384 + lgoff;
    const char* Bg = Bb + (size_t)bx * 16384 + lgoff;
#pragma unroll
    for (int j = 0; j < 4; ++j) {
      gl_lds16(Ag + j * 4096, (char*)As + j * 4096 + lloff);
      gl_lds16(Bg + j * 4096, (char*)Bs + j * 4096 + lloff);
    }
  }
  __syncthreads();   // vmcnt(0): tile 0 staged

  const f32x4 zv4 = {0.f, 0.f, 0.f, 0.f};   // persistent zero C-operand
  f32x4 acc[4][4];

  for (int it = 0; it < 8; ++it) {
    const int p = it & 1;

    if (it < 7) {    // issue next tile's stage into the other buffer; lands by tile-end barrier
      const int by = sp * 8 + it + 1;
      const int bx = (by + T) & 63;
      const char* Ag = Ab + (size_t)by * 16384 + lgoff;
      const char* Bg = Bb + (size_t)bx * 16384 + lgoff;
      char* Ad = (char*)As + (p ^ 1) * 16384 + lloff;
      char* Bd = (char*)Bs + (p ^ 1) * 16384 + lloff;
#pragma unroll
      for (int j = 0; j < 4; ++j) {
        gl_lds16(Ag + j * 4096, Ad + j * 4096);
        gl_lds16(Bg + j * 4096, Bd + j * 4096);
      }
    }

    const unsigned char* Abuf = (const unsigned char*)As + p * 16384;
    const unsigned char* Bbuf = (const unsigned char*)Bs + p * 16384;

#if __has_builtin(__builtin_amdgcn_mfma_scale_f32_16x16x128_f8f6f4)
    // ---- issue ALL fragment loads first (16 x ds_read_b128) ----
    i32x8v af[4], bf[4];
#pragma unroll
    for (int c = 0; c < 4; ++c) bf[c] = ld_frag32(Bbuf, brow + c * 2048, q2, x7);
#pragma unroll
    for (int r = 0; r < 4; ++r) af[r] = ld_frag32(Abuf, arow + r * 2048, q2, x7);

    // ---- previous window's epilogue: reg-only, fills the ds_read shadow ----
    if (it) epi(acc, dreg);

    // ---- 16 MFMA, fresh-C (D != C), wave priority raised (T5) ----
    __builtin_amdgcn_s_setprio(1);
#pragma unroll
    for (int r = 0; r < 4; ++r)
#pragma unroll
      for (int c = 0; c < 4; ++c)
        acc[r][c] = __builtin_amdgcn_mfma_scale_f32_16x16x128_f8f6f4(
            af[r], bf[c], zv4, 0, 0,                       // C = shared zero quad
            0, 0x7F7F7F7F, 0, 0x7F7F7F7F);                 // unit scales (e8m0 127 = 2^0)
    __builtin_amdgcn_s_setprio(0);
#else
    {
      if (it) epi(acc, dreg);
      const f32x4 zv = {0.f, 0.f, 0.f, 0.f};
#pragma unroll
      for (int r = 0; r < 4; ++r)
#pragma unroll
        for (int c = 0; c < 4; ++c) acc[r][c] = zv;
#pragma unroll
      for (int ks = 0; ks < 4; ++ks) {
        long a[4], b[4];
        const int off = (((ks * 2 + qh) ^ x7) * 16) + ql8;   // swizzled 8B k-chunk
#pragma unroll
        for (int r = 0; r < 4; ++r)
          a[r] = *reinterpret_cast<const long*>(Abuf + arow + r * 2048 + off);
#pragma unroll
        for (int c = 0; c < 4; ++c)
          b[c] = *reinterpret_cast<const long*>(Bbuf + brow + c * 2048 + off);
#pragma unroll
        for (int r = 0; r < 4; ++r)
#pragma unroll
          for (int c = 0; c < 4; ++c)
            acc[r][c] = __builtin_amdgcn_mfma_f32_16x16x32_fp8_fp8(a[r], b[c], acc[r][c], 0, 0, 0);
      }
    }
#endif

    __syncthreads();   // one barrier/tile: drains ds_reads of buf p AND stage into buf p^1
  }

  // final window's epilogue (pipeline drain)
  epi(acc, dreg);

  // ---- single flush: shfl tree over 4-lane collision groups -> LDS -> global ----
  const int  Qoff = (wcol - wrow) * 64 + 127;
  const int  v    = l15 - quad * 4;
  const bool leader = (quad == 0) || (l15 <= 3);
  const bool ok1 = (l15 <= 11) && (quad <= 2);
  const bool ok2 = (l15 <= 7)  && (quad <= 1);

#pragma unroll
  for (int dlt = -3; dlt <= 3; ++dlt) {
#pragma unroll
    for (int g = 0; g < 4; ++g) {
      float s = dreg[(dlt + 3) * 4 + g];
      float t1 = __shfl_down(s, 20); s += ok1 ? t1 : 0.0f;  // partner quad+1
      float t2 = __shfl_down(s, 40); s += ok2 ? t2 : 0.0f;  // partners quad+2, quad+3
      int ld = Qoff + dlt * 16 - g + v;
      if (leader) unsafeAtomicAdd(&part[w][ld], s);         // distinct ld per leader
    }
  }
  __syncthreads();

  // band-0 slot 127 corresponds to d=0 only, which the tail skips
  if (t < 255) {
    float vv = part[0][t] + part[1][t] + part[2][t] + part[3][t];
    unsafeAtomicAdd(&bandsum[T * 256 + t], vv);
  }

  // ---- last-block-done detection (device-scope atomics; counter bump after
  //      the bandsum adds; no release fence needed) ----
  __syncthreads();
  if (t == 0) lastFlag = (atomicAdd(counter, 1u) == 511u) ? 1u : 0u;
  __syncthreads();
  if (!lastFlag) return;

  // ================= scalar tail (one block, 256 threads, batched loads) =================
  __threadfence();          // acquire: invalidate stale lines so bandsum loads are fresh
  float* sm = part[0];

  float lp[32];
#pragma unroll
  for (int k = 0; k < 32; ++k) lp[k] = logit_p[t + 256 * k];

  float m = lp[0];
#pragma unroll
  for (int k = 1; k < 32; ++k) m = fmaxf(m, lp[k]);
#pragma unroll
  for (int off = 32; off; off >>= 1) m = fmaxf(m, __shfl_down(m, off));
  if (lane == 0) sm[w] = m;
  __syncthreads();
  m = fmaxf(fmaxf(sm[0], sm[1]), fmaxf(sm[2], sm[3]));
  __syncthreads();

  float s = 0.0f;
#pragma unroll
  for (int k = 0; k < 32; ++k) s += __expf(lp[k] - m);
#pragma unroll
  for (int off = 32; off; off >>= 1) s += __shfl_down(s, off);
  if (lane == 0) sm[w] = s;
  __syncthreads();
  s = sm[0] + sm[1] + sm[2] + sm[3];
  float lse_p = m + __logf(s);
  __syncthreads();

  // thread t handles d = t + 256k: d>>7 = (t>>7) + 2k, d&127 = t&127
  const int o  = t & 127;
  const int hi = t >> 7;
  float bs1[32], bs2[32];
#pragma unroll
  for (int k = 0; k < 32; ++k) {
    int Ta = hi + 2 * k;
    bs1[k] = bandsum[Ta * 256 + o + 127];
    bs2[k] = o ? bandsum[((Ta + 1) & 63) * 256 + o - 1] : 0.0f;
  }
  float tacc = 0.0f;
#pragma unroll
  for (int k = 0; k < 32; ++k) {
    if (t == 0 && k == 0) continue;   // d=0 excluded
    float se = bs1[k] + bs2[k];
    float x = __logf(se) + lse_p;
    tacc += fmaxf(x, 0.0f) + __logf(1.0f + __expf(-fabsf(x)));
  }
#pragma unroll
  for (int off = 32; off; off >>= 1) tacc += __shfl_down(tacc, off);
  if (lane == 0) sm[w] = tacc;
  __syncthreads();
  if (t == 0) out[0] = (sm[0] + sm[1] + sm[2] + sm[3]) * (1.0f / 8191.0f);
}

// ---------------- launcher ----------------
extern "C" void kernel_launch(void* const* d_in, const int* in_sizes, int n_in,
                              void* d_out, int out_size, void* d_ws, size_t ws_size,
                              hipStream_t stream) {
  const float* enc = (const float*)d_in[0];
  const float* dec = (const float*)d_in[1];
  float* ws = (float*)d_ws;

  float*    logit_p = ws;                               // 8192
  float*    bandsum = ws + 8192;                        // 64*256 = 16384
  unsigned* counter = (unsigned*)(ws + 8192 + 16384);   // 1 (+pad)
  uint2*    A8      = (uint2*)(ws + 8192 + 16384 + 256);     // 8192x128 fp8 = 1 MB
  uint2*    B8      = (uint2*)((char*)A8 + 1048576);
  float*    out     = (float*)d_out;

  k_prep<<<NN / 16, 256, 0, stream>>>(enc, dec, A8, B8, logit_p, bandsum, counter);
  dim3 grid(64, 8);
  k_main<<<grid, 256, 0, stream>>>((const unsigned char*)A8, (const unsigned char*)B8,
                                   bandsum, logit_p, counter, out);
}